// Round 8
// baseline (232.979 us; speedup 1.0000x reference)
//
#include <hip/hip_runtime.h>
#include <hip/hip_bf16.h>
#include <stdint.h>

#define S_LEN 2048
#define HID 2880
#define NH 64
#define NKV 8
#define HD 64
#define NQ (NH * HD)     // 4096
#define NKVD (NKV * HD)  // 512
#define SCALE 0.125f
#define QBK 64

typedef unsigned short u16;
typedef __attribute__((ext_vector_type(8))) short short8;
typedef __attribute__((ext_vector_type(4))) float floatx4;

__device__ __forceinline__ u16 f2bf(float f) {
  union { float f; unsigned u; } x; x.f = f;
  unsigned r = x.u + 0x7fffu + ((x.u >> 16) & 1u);
  return (u16)(r >> 16);
}
__device__ __forceinline__ float bf2f(u16 u) {
  union { unsigned u; float f; } x; x.u = ((unsigned)u) << 16;
  return x.f;
}

// bijective XCD-aware block swizzle (m204): contiguous chunk per XCD
__device__ __forceinline__ int xcd_swz(int orig, int nwg) {
  int q = nwg >> 3, r = nwg & 7, xcd = orig & 7, lid = orig >> 3;
  return (xcd < r ? xcd * (q + 1) : r * (q + 1) + (xcd - r) * q) + lid;
}

// global -> LDS async copy, 16B per lane. LDS dest is wave-uniform base;
// HW writes lane i at base + i*16.
__device__ __forceinline__ void gl2lds16(const void* g, void* l) {
  __builtin_amdgcn_global_load_lds(
      (__attribute__((address_space(1))) unsigned int*)(uintptr_t)g,
      (__attribute__((address_space(3))) unsigned int*)(unsigned int)(uintptr_t)l,
      16, 0, 0);
}

// ---------------- convert f32 -> bf16 ----------------
__global__ void k_convert(const float* __restrict__ in, u16* __restrict__ out, int n4) {
  int i = blockIdx.x * blockDim.x + threadIdx.x;
  if (i >= n4) return;
  float4 v = *((const float4*)in + i);
  ushort4 o;
  o.x = f2bf(v.x); o.y = f2bf(v.y); o.z = f2bf(v.z); o.w = f2bf(v.w);
  *(ushort4*)(out + (size_t)i * 4) = o;
}

// ---------------- transpose f32[R][C] -> bf16[C][R] ----------------
__global__ void k_transpose(const float* __restrict__ in, u16* __restrict__ out, int R, int C) {
  __shared__ float tile[32][33];
  int bx = blockIdx.x * 32, by = blockIdx.y * 32;
  int tx = threadIdx.x, ty = threadIdx.y;
#pragma unroll
  for (int i = 0; i < 4; ++i)
    tile[ty + i * 8][tx] = in[(long)(by + ty + i * 8) * C + bx + tx];
  __syncthreads();
#pragma unroll
  for (int i = 0; i < 4; ++i)
    out[(long)(bx + ty + i * 8) * R + by + tx] = f2bf(tile[tx][ty + i * 8]);
}

// ================= 256x256 BK=64 8-wave phase-split QKV GEMM =================
// T3+T4+T5+T2 combo (m201-derived, conservatively restructured):
//  - 2 tile-buffers As/Bs[2][256][64]; group T reads buf(T&1).
//  - Group entry: own-wave vmcnt(8) (tile T landed, tile T+1's 8 loads still in
//    flight) -> s_barrier (joins all waves' waits). Never drains to 0 mid-loop.
//  - 4 quadrant-phases per K-tile: {12 ds_read_b128 -> s_barrier -> setprio(1)
//    -> 16 MFMA -> setprio(0) -> sched_barrier(0)}.
//  - Group end: s_barrier, then STAGE(T+2) into the just-consumed buffer
//    (legal: all waves passed the end barrier; loads land during group T+1
//    which reads the OTHER buffer; consumed at group T+2 after its vmcnt).
//  - T2 swizzle: 16B slot s of row r stored at s^(r&7). gl2lds dest is linear,
//    so the SOURCE k-slot is pre-swizzled per lane; ds_read applies the same
//    XOR (involution; both-sides rule). Banks: slot*4+i, rows invisible
//    (128B rows = exact wrap); per b128 each slot serves 8 lanes = the 8-cyc
//    BW floor, no excess serialization.
// FP order along K identical to the 128x32 core (kt sequential, kk inner):
// output must be bit-identical to r7.
__global__ __launch_bounds__(512) void k_gemm_qkv256(
    const u16* __restrict__ hsb, const u16* __restrict__ wqt,
    const u16* __restrict__ wkt, const u16* __restrict__ wvt,
    const float* __restrict__ bq, const float* __restrict__ bk, const float* __restrict__ bv,
    const float* __restrict__ cosb, const float* __restrict__ sinb,
    u16* __restrict__ qbuf, u16* __restrict__ kbuf, u16* __restrict__ vtbuf) {
  __shared__ __align__(16) u16 As[2][256][64];
  __shared__ __align__(16) u16 Bs[2][256][64];
  const int t = threadIdx.x;            // 0..511
  const int w = t >> 6, l = t & 63;
  const int fr = l & 15, g = l >> 4, fq = g * 4;
  const int wr = (w >> 2) * 128, wc = (w & 3) * 64;   // wave tile 128x64 (2Mx4N)
  const int srow8 = t >> 3;                            // staging row in 64-row round
  const int sslot = ((t & 7) ^ (srow8 & 7)) * 8;       // pre-swizzled source slot (elems)
  const int swa = (fr & 7) * 8;                        // read-side row-XOR (elems)

  int sw = xcd_swz(blockIdx.x, gridDim.x);             // 160 blocks = 8 bm x 20 bn
  int bm = (sw & 7) * 256, bn = (sw >> 3) * 256;
  const u16* Bt; const float* bias;
  if (bn < NQ)             { Bt = wqt + (long)bn * HID;               bias = bq + bn; }
  else if (bn < NQ + NKVD) { Bt = wkt + (long)(bn - NQ) * HID;        bias = bk + (bn - NQ); }
  else                     { Bt = wvt + (long)(bn - NQ - NKVD) * HID; bias = bv + (bn - NQ - NKVD); }
  const u16* Ab = hsb + (long)bm * HID;

  floatx4 acc[8][4];
  floatx4 zero = {0.f, 0.f, 0.f, 0.f};
#pragma unroll
  for (int m = 0; m < 8; ++m)
#pragma unroll
    for (int n = 0; n < 4; ++n) acc[m][n] = zero;

#define QSTAGE(buf, kt) do {                                              \
    long ko_ = (long)(kt) * QBK + sslot;                                  \
    _Pragma("unroll")                                                     \
    for (int q_ = 0; q_ < 4; ++q_) {                                      \
      gl2lds16(Ab + (long)(q_ * 64 + srow8) * HID + ko_,                  \
               &As[buf][q_ * 64 + w * 8][0]);                             \
      gl2lds16(Bt + (long)(q_ * 64 + srow8) * HID + ko_,                  \
               &Bs[buf][q_ * 64 + w * 8][0]);                             \
    } } while (0)

#define QPHASE(cb, ih, jh) do {                                           \
    short8 af_[4][2], bf_[2][2];                                          \
    _Pragma("unroll")                                                     \
    for (int i_ = 0; i_ < 4; ++i_)                                        \
      _Pragma("unroll")                                                   \
      for (int kk_ = 0; kk_ < 2; ++kk_) {                                 \
        int ar_ = wr + (ih) * 64 + i_ * 16 + fr;                          \
        af_[i_][kk_] = *(const short8*)&As[cb][ar_][(kk_ * 32 + g * 8) ^ swa]; \
      }                                                                   \
    _Pragma("unroll")                                                     \
    for (int j_ = 0; j_ < 2; ++j_)                                        \
      _Pragma("unroll")                                                   \
      for (int kk_ = 0; kk_ < 2; ++kk_) {                                 \
        int br_ = wc + (jh) * 32 + j_ * 16 + fr;                          \
        bf_[j_][kk_] = *(const short8*)&Bs[cb][br_][(kk_ * 32 + g * 8) ^ swa]; \
      }                                                                   \
    __builtin_amdgcn_s_barrier();                                         \
    __builtin_amdgcn_s_setprio(1);                                        \
    _Pragma("unroll")                                                     \
    for (int i_ = 0; i_ < 4; ++i_)                                        \
      _Pragma("unroll")                                                   \
      for (int j_ = 0; j_ < 2; ++j_)                                      \
        _Pragma("unroll")                                                 \
        for (int kk_ = 0; kk_ < 2; ++kk_)                                 \
          acc[(ih) * 4 + i_][(jh) * 2 + j_] =                             \
              __builtin_amdgcn_mfma_f32_16x16x32_bf16(                    \
                  af_[i_][kk_], bf_[j_][kk_],                             \
                  acc[(ih) * 4 + i_][(jh) * 2 + j_], 0, 0, 0);            \
    __builtin_amdgcn_s_setprio(0);                                        \
    __builtin_amdgcn_sched_barrier(0);                                    \
  } while (0)

  const int nk = HID / QBK;             // 45
  QSTAGE(0, 0);
  QSTAGE(1, 1);
  for (int kt = 0; kt < nk; ++kt) {
    const int cb = kt & 1;
    if (kt + 1 < nk) { asm volatile("s_waitcnt vmcnt(8)" ::: "memory"); }
    else             { asm volatile("s_waitcnt vmcnt(0)" ::: "memory"); }
    __builtin_amdgcn_s_barrier();       // tile kt resident for all waves
    QPHASE(cb, 0, 0);
    QPHASE(cb, 0, 1);
    QPHASE(cb, 1, 0);
    QPHASE(cb, 1, 1);
    __builtin_amdgcn_s_barrier();       // all waves done reading buf(kt&1)
    if (kt + 2 < nk) QSTAGE(cb, kt + 2);
  }
#undef QPHASE
#undef QSTAGE

  // ---- epilogue: bias + RoPE scatter (q/k) or transposed V scatter ----
  if (bn < NQ + NKVD) {
    int ng0 = bn + wc;                  // one 64-col head per wave
    u16* hbase = (ng0 < NQ) ? qbuf + (long)(ng0 >> 6) * S_LEN * HD
                            : kbuf + (long)((ng0 - NQ) >> 6) * S_LEN * HD;
#pragma unroll
    for (int m = 0; m < 8; ++m)
#pragma unroll
      for (int rr = 0; rr < 4; ++rr) {
        int srow = bm + wr + m * 16 + fq + rr;
        const float* crow = cosb + (long)srow * HD;
        const float* srw  = sinb + (long)srow * HD;
#pragma unroll
        for (int j = 0; j < 2; ++j) {
          int dlo = j * 16 + fr;        // in [0,32)
          float c  = crow[dlo];
          float si = srw[dlo];
          float xl = acc[m][j][rr]     + bias[wc + j * 16 + fr];
          float xh = acc[m][j + 2][rr] + bias[wc + (j + 2) * 16 + fr];
          hbase[(long)srow * HD + dlo]      = f2bf(xl * c - xh * si);
          hbase[(long)srow * HD + dlo + 32] = f2bf(xh * c + xl * si);
        }
      }
  } else {
#pragma unroll
    for (int m = 0; m < 8; ++m)
#pragma unroll
      for (int n = 0; n < 4; ++n) {
        int ncol = wc + n * 16 + fr;
        int n3 = bn + ncol - NQ - NKVD;
        float bsv = bias[ncol];
#pragma unroll
        for (int rr = 0; rr < 4; ++rr) {
          int srow = bm + wr + m * 16 + fq + rr;
          vtbuf[(long)(n3 >> 6) * HD * S_LEN + (long)(n3 & 63) * S_LEN + srow] =
              f2bf(acc[m][n][rr] + bsv);
        }
      }
  }
}

// ---------------- 128x128 bf16 MFMA GEMM core (r7: ring-3 + counted vmcnt + swz) ----------------
__device__ __forceinline__ void gemm_tile(const u16* __restrict__ Abase, int lda,
                                          const u16* __restrict__ Bbase, int ldb,
                                          int kloop, floatx4 acc[4][4]) {
  __shared__ __align__(16) u16 As[3][128][32];
  __shared__ __align__(16) u16 Bs[3][128][32];
  const int t = threadIdx.x;
  const int w = t >> 6, l = t & 63;
  const int srow = w * 16 + (l >> 2);
  const int scol = (((l & 3) ^ ((l >> 3) & 3))) * 8;
  const int wr = (w >> 1) * 64, wc = (w & 1) * 64;
  const int fr = l & 15;
  const int fk8 = (((l >> 4) ^ ((l >> 1) & 3))) * 8;
  floatx4 zero = {0.f, 0.f, 0.f, 0.f};
#pragma unroll
  for (int i = 0; i < 4; ++i)
#pragma unroll
    for (int j = 0; j < 4; ++j) acc[i][j] = zero;

  const u16* Ar0 = Abase + (long)srow * lda + scol;
  const u16* Ar1 = Abase + (long)(64 + srow) * lda + scol;
  const u16* Br0 = Bbase + (long)srow * ldb + scol;
  const u16* Br1 = Bbase + (long)(64 + srow) * ldb + scol;

#define STAGE(buf, kt) do {                              \
    long ko_ = (long)(kt) * 32;                          \
    gl2lds16(Ar0 + ko_, &As[buf][w * 16][0]);            \
    gl2lds16(Ar1 + ko_, &As[buf][64 + w * 16][0]);       \
    gl2lds16(Br0 + ko_, &Bs[buf][w * 16][0]);            \
    gl2lds16(Br1 + ko_, &Bs[buf][64 + w * 16][0]);       \
  } while (0)

  const int nk = kloop >> 5;
  STAGE(0, 0);
  STAGE(1, 1);
  int cur = 0, nxt = 1, fut = 2;
  for (int kt = 0; kt < nk; ++kt) {
    if (kt + 1 < nk) { asm volatile("s_waitcnt vmcnt(4)" ::: "memory"); }
    else             { asm volatile("s_waitcnt vmcnt(0)" ::: "memory"); }
    asm volatile("s_barrier" ::: "memory");
    if (kt + 2 < nk) STAGE(fut, kt + 2);
    short8 af[4], bf8[4];
#pragma unroll
    for (int i = 0; i < 4; ++i) af[i] = *(const short8*)&As[cur][wr + i * 16 + fr][fk8];
#pragma unroll
    for (int j = 0; j < 4; ++j) bf8[j] = *(const short8*)&Bs[cur][wc + j * 16 + fr][fk8];
#pragma unroll
    for (int i = 0; i < 4; ++i)
#pragma unroll
      for (int j = 0; j < 4; ++j)
        acc[i][j] = __builtin_amdgcn_mfma_f32_16x16x32_bf16(af[i], bf8[j], acc[i][j], 0, 0, 0);
    int tmp = cur; cur = nxt; nxt = fut; fut = tmp;
  }
#undef STAGE
}

// ---------------- sliding-window GQA attention with sinks ----------------
__global__ __launch_bounds__(256) void k_attn(
    const u16* __restrict__ qb, const u16* __restrict__ kb, const u16* __restrict__ vtb,
    const float* __restrict__ sinks, u16* __restrict__ ao) {
  __shared__ __align__(16) u16 Kl[192][72];
  __shared__ __align__(16) u16 Vl[64][200];
  int t = threadIdx.x;
  int h = blockIdx.y, kvh = h >> 3;
  int qs = blockIdx.x * 64;
  int kstart = qs - 128;
  const u16* kbase = kb + (long)kvh * S_LEN * HD;
  const u16* vbase = vtb + (long)kvh * HD * S_LEN;
#pragma unroll
  for (int it = 0; it < 6; ++it) {
    int idx = t + it * 256;
    int c = idx >> 3, dc = (idx & 7) * 8;
    int j = kstart + c;
    short8 v = {0, 0, 0, 0, 0, 0, 0, 0};
    if (j >= 0) v = *(const short8*)(kbase + (long)j * HD + dc);
    *(short8*)&Kl[c][dc] = v;
  }
#pragma unroll
  for (int it = 0; it < 6; ++it) {
    int idx = t + it * 256;
    int d = idx / 24, c8 = idx % 24;
    int c = c8 * 8;
    int j = kstart + c;
    short8 v = {0, 0, 0, 0, 0, 0, 0, 0};
    if (j >= 0) v = *(const short8*)(vbase + (long)d * S_LEN + j);
    *(short8*)&Vl[d][c] = v;
  }
  __syncthreads();

  int w = t >> 6, l = t & 63;
  int fr = l & 15, fk8 = (l >> 4) * 8, fq = (l >> 4) * 4;
  const u16* qrow = qb + (long)h * S_LEN * HD + (long)(qs + w * 16 + fr) * HD;
  short8 a0 = *(const short8*)(qrow + fk8);
  short8 a1 = *(const short8*)(qrow + 32 + fk8);
  floatx4 sc[12];
#pragma unroll
  for (int ct = 0; ct < 12; ++ct) {
    floatx4 z = {0.f, 0.f, 0.f, 0.f};
    short8 b0 = *(const short8*)&Kl[ct * 16 + fr][fk8];
    short8 b1 = *(const short8*)&Kl[ct * 16 + fr][32 + fk8];
    z = __builtin_amdgcn_mfma_f32_16x16x32_bf16(a0, b0, z, 0, 0, 0);
    z = __builtin_amdgcn_mfma_f32_16x16x32_bf16(a1, b1, z, 0, 0, 0);
    sc[ct] = z;
  }
  __syncthreads();

  u16* Pw = &Kl[0][0] + w * 16 * 200;
  float snk = sinks[h];
#pragma unroll
  for (int r = 0; r < 4; ++r) {
    int rloc = w * 16 + fq + r;
    int cmin = rloc + 1;
    int jmin = 128 - qs;
    if (jmin > cmin) cmin = jmin;
    int cmax = rloc + 128;
    float vals[12];
    float mx = snk;
#pragma unroll
    for (int ct = 0; ct < 12; ++ct) {
      int c = ct * 16 + fr;
      float v = (c >= cmin && c <= cmax) ? sc[ct][r] * SCALE : -1e30f;
      vals[ct] = v;
      mx = fmaxf(mx, v);
    }
#pragma unroll
    for (int m = 1; m < 16; m <<= 1) mx = fmaxf(mx, __shfl_xor(mx, m));
    float e[12], sum = 0.f;
#pragma unroll
    for (int ct = 0; ct < 12; ++ct) { e[ct] = __expf(vals[ct] - mx); sum += e[ct]; }
#pragma unroll
    for (int m = 1; m < 16; m <<= 1) sum += __shfl_xor(sum, m);
    sum += __expf(snk - mx);
    float inv = 1.f / sum;
#pragma unroll
    for (int ct = 0; ct < 12; ++ct)
      Pw[(fq + r) * 200 + ct * 16 + fr] = f2bf(e[ct] * inv);
  }
  __syncthreads();

  floatx4 o[4];
  floatx4 zero = {0.f, 0.f, 0.f, 0.f};
#pragma unroll
  for (int cd = 0; cd < 4; ++cd) o[cd] = zero;
#pragma unroll
  for (int kk = 0; kk < 6; ++kk) {
    short8 pa = *(const short8*)(Pw + fr * 200 + kk * 32 + fk8);
#pragma unroll
    for (int cd = 0; cd < 4; ++cd) {
      short8 bv8 = *(const short8*)&Vl[cd * 16 + fr][kk * 32 + fk8];
      o[cd] = __builtin_amdgcn_mfma_f32_16x16x32_bf16(pa, bv8, o[cd], 0, 0, 0);
    }
  }
#pragma unroll
  for (int cd = 0; cd < 4; ++cd)
#pragma unroll
    for (int r = 0; r < 4; ++r) {
      int srow = qs + w * 16 + fq + r;
      ao[(long)srow * NQ + h * HD + cd * 16 + fr] = f2bf(o[cd][r]);
    }
}

// ---------------- output projection GEMM (r7 unchanged) ----------------
__global__ __launch_bounds__(256) void k_gemm_out(
    const u16* __restrict__ attn, const u16* __restrict__ wot,
    const float* __restrict__ bo, float* __restrict__ out) {
  int sw = xcd_swz(blockIdx.x, gridDim.x);
  int bm = (sw & 15) * 128, bn = (sw >> 4) * 128;
  floatx4 acc[4][4];
  gemm_tile(attn + (long)bm * NQ, NQ, wot + (long)bn * NQ, NQ, NQ, acc);
  int t = threadIdx.x, w = t >> 6, l = t & 63;
  int wr = (w >> 1) * 64, wc = (w & 1) * 64, fr = l & 15, fq = (l >> 4) * 4;
#pragma unroll
  for (int i = 0; i < 4; ++i)
#pragma unroll
    for (int j = 0; j < 4; ++j) {
      int ng = bn + wc + j * 16 + fr;
      if (ng >= HID) continue;
      float bsv = bo[ng];
#pragma unroll
      for (int r = 0; r < 4; ++r) {
        int srow = bm + wr + i * 16 + fq + r;
        out[(long)srow * HID + ng] = acc[i][j][r] + bsv;
      }
    }
}

extern "C" void kernel_launch(void* const* d_in, const int* in_sizes, int n_in,
                              void* d_out, int out_size, void* d_ws, size_t ws_size,
                              hipStream_t stream) {
  const float* hs    = (const float*)d_in[0];
  const float* cosb  = (const float*)d_in[1];
  const float* sinb  = (const float*)d_in[2];
  const float* wq    = (const float*)d_in[3];
  const float* bq    = (const float*)d_in[4];
  const float* wk    = (const float*)d_in[5];
  const float* bk    = (const float*)d_in[6];
  const float* wv    = (const float*)d_in[7];
  const float* bv    = (const float*)d_in[8];
  const float* wo    = (const float*)d_in[9];
  const float* bo    = (const float*)d_in[10];
  const float* sinks = (const float*)d_in[11];
  float* out = (float*)d_out;

  char* p = (char*)d_ws;
  u16* hsb   = (u16*)p; p += (size_t)S_LEN * HID * 2;
  u16* wqt   = (u16*)p; p += (size_t)NQ * HID * 2;
  u16* wkt   = (u16*)p; p += (size_t)NKVD * HID * 2;
  u16* wvt   = (u16*)p; p += (size_t)NKVD * HID * 2;
  u16* wot   = (u16*)p; p += (size_t)2944 * NQ * 2;
  u16* qbuf  = (u16*)p; p += (size_t)NH * S_LEN * HD * 2;
  u16* kbuf  = (u16*)p; p += (size_t)NKV * S_LEN * HD * 2;
  u16* vtbuf = (u16*)p; p += (size_t)NKV * HD * S_LEN * 2;
  u16* abuf  = (u16*)p; p += (size_t)S_LEN * NQ * 2;

  k_convert<<<(S_LEN * HID / 4 + 255) / 256, 256, 0, stream>>>(hs, hsb, S_LEN * HID / 4);
  k_transpose<<<dim3(NQ / 32, HID / 32), dim3(32, 8), 0, stream>>>(wq, wqt, HID, NQ);
  k_transpose<<<dim3(NKVD / 32, HID / 32), dim3(32, 8), 0, stream>>>(wk, wkt, HID, NKVD);
  k_transpose<<<dim3(NKVD / 32, HID / 32), dim3(32, 8), 0, stream>>>(wv, wvt, HID, NKVD);
  k_transpose<<<dim3(HID / 32, NQ / 32), dim3(32, 8), 0, stream>>>(wo, wot, NQ, HID);
  k_gemm_qkv256<<<8 * 20, 512, 0, stream>>>(
      hsb, wqt, wkt, wvt, bq, bk, bv, cosb, sinb, qbuf, kbuf, vtbuf);
  k_attn<<<dim3(S_LEN / 64, NH), 256, 0, stream>>>(qbuf, kbuf, vtbuf, sinks, abuf);
  k_gemm_out<<<23 * 16, 256, 0, stream>>>(abuf, wot, bo, out);
}

// Round 9
// 229.569 us; speedup vs baseline: 1.0149x; 1.0149x over previous
//
#include <hip/hip_runtime.h>
#include <hip/hip_bf16.h>
#include <stdint.h>

#define S_LEN 2048
#define HID 2880
#define NH 64
#define NKV 8
#define HD 64
#define NQ (NH * HD)     // 4096
#define NKVD (NKV * HD)  // 512
#define SCALE 0.125f
#define QBK 64

typedef unsigned short u16;
typedef __attribute__((ext_vector_type(8))) short short8;
typedef __attribute__((ext_vector_type(4))) float floatx4;

__device__ __forceinline__ u16 f2bf(float f) {
  union { float f; unsigned u; } x; x.f = f;
  unsigned r = x.u + 0x7fffu + ((x.u >> 16) & 1u);
  return (u16)(r >> 16);
}
__device__ __forceinline__ float bf2f(u16 u) {
  union { unsigned u; float f; } x; x.u = ((unsigned)u) << 16;
  return x.f;
}

// bijective XCD-aware block swizzle (m204): contiguous chunk per XCD
__device__ __forceinline__ int xcd_swz(int orig, int nwg) {
  int q = nwg >> 3, r = nwg & 7, xcd = orig & 7, lid = orig >> 3;
  return (xcd < r ? xcd * (q + 1) : r * (q + 1) + (xcd - r) * q) + lid;
}

// global -> LDS async copy, 16B per lane. LDS dest is wave-uniform base;
// HW writes lane i at base + i*16.
__device__ __forceinline__ void gl2lds16(const void* g, void* l) {
  __builtin_amdgcn_global_load_lds(
      (__attribute__((address_space(1))) unsigned int*)(uintptr_t)g,
      (__attribute__((address_space(3))) unsigned int*)(unsigned int)(uintptr_t)l,
      16, 0, 0);
}

// ---------------- convert f32 -> bf16 ----------------
__global__ void k_convert(const float* __restrict__ in, u16* __restrict__ out, int n4) {
  int i = blockIdx.x * blockDim.x + threadIdx.x;
  if (i >= n4) return;
  float4 v = *((const float4*)in + i);
  ushort4 o;
  o.x = f2bf(v.x); o.y = f2bf(v.y); o.z = f2bf(v.z); o.w = f2bf(v.w);
  *(ushort4*)(out + (size_t)i * 4) = o;
}

// ---------------- transpose f32[R][C] -> bf16[C][R] ----------------
__global__ void k_transpose(const float* __restrict__ in, u16* __restrict__ out, int R, int C) {
  __shared__ float tile[32][33];
  int bx = blockIdx.x * 32, by = blockIdx.y * 32;
  int tx = threadIdx.x, ty = threadIdx.y;
#pragma unroll
  for (int i = 0; i < 4; ++i)
    tile[ty + i * 8][tx] = in[(long)(by + ty + i * 8) * C + bx + tx];
  __syncthreads();
#pragma unroll
  for (int i = 0; i < 4; ++i)
    out[(long)(bx + ty + i * 8) * R + by + tx] = f2bf(tile[tx][ty + i * 8]);
}

// ================= 256x256 BK=64 8-wave phase-split QKV GEMM (v2) =============
// r8 kernel with ONE change: 2 phases per K-tile with cached fragments.
//  - phase 0: read ALL B n-frags (8 ds_read_b128) + A-half0 (8) -> barrier ->
//    32 MFMA (half0 x all-n x 2kk).
//  - phase 1: read A-half1 (8; B stays in regs) -> barrier -> 32 MFMA (half1).
//  => 24 reads per K-tile per wave (the geometric minimum for a 128x64 wave
//  tile) vs r8's 48 (each half read twice). LDS-read/SIMD/K-tile 576->288cy
//  vs MFMA 614cy: reads now fully hideable under MFMA.
// Accumulation order per acc element unchanged (kt asc, kk inner) ->
// bit-identical output to r7/r8.
// Sync scheme unchanged from r8 (proven): group entry own-vmcnt(8) -> barrier;
// group end barrier -> STAGE(t+2) into just-consumed buffer.
__global__ __launch_bounds__(512) void k_gemm_qkv256(
    const u16* __restrict__ hsb, const u16* __restrict__ wqt,
    const u16* __restrict__ wkt, const u16* __restrict__ wvt,
    const float* __restrict__ bq, const float* __restrict__ bk, const float* __restrict__ bv,
    const float* __restrict__ cosb, const float* __restrict__ sinb,
    u16* __restrict__ qbuf, u16* __restrict__ kbuf, u16* __restrict__ vtbuf) {
  __shared__ __align__(16) u16 As[2][256][64];
  __shared__ __align__(16) u16 Bs[2][256][64];
  const int t = threadIdx.x;            // 0..511
  const int w = t >> 6, l = t & 63;
  const int fr = l & 15, g = l >> 4, fq = g * 4;
  const int wr = (w >> 2) * 128, wc = (w & 3) * 64;   // wave tile 128x64 (2Mx4N)
  const int srow8 = t >> 3;                            // staging row in 64-row round
  const int sslot = ((t & 7) ^ (srow8 & 7)) * 8;       // pre-swizzled source slot (elems)
  const int swa = (fr & 7) * 8;                        // read-side row-XOR (elems)

  int sw = xcd_swz(blockIdx.x, gridDim.x);             // 160 blocks = 8 bm x 20 bn
  int bm = (sw & 7) * 256, bn = (sw >> 3) * 256;
  const u16* Bt; const float* bias;
  if (bn < NQ)             { Bt = wqt + (long)bn * HID;               bias = bq + bn; }
  else if (bn < NQ + NKVD) { Bt = wkt + (long)(bn - NQ) * HID;        bias = bk + (bn - NQ); }
  else                     { Bt = wvt + (long)(bn - NQ - NKVD) * HID; bias = bv + (bn - NQ - NKVD); }
  const u16* Ab = hsb + (long)bm * HID;

  floatx4 acc[8][4];
  floatx4 zero = {0.f, 0.f, 0.f, 0.f};
#pragma unroll
  for (int m = 0; m < 8; ++m)
#pragma unroll
    for (int n = 0; n < 4; ++n) acc[m][n] = zero;

#define QSTAGE(buf, kt) do {                                              \
    long ko_ = (long)(kt) * QBK + sslot;                                  \
    _Pragma("unroll")                                                     \
    for (int q_ = 0; q_ < 4; ++q_) {                                      \
      gl2lds16(Ab + (long)(q_ * 64 + srow8) * HID + ko_,                  \
               &As[buf][q_ * 64 + w * 8][0]);                             \
      gl2lds16(Bt + (long)(q_ * 64 + srow8) * HID + ko_,                  \
               &Bs[buf][q_ * 64 + w * 8][0]);                             \
    } } while (0)

  const int nk = HID / QBK;             // 45
  QSTAGE(0, 0);
  QSTAGE(1, 1);
  for (int kt = 0; kt < nk; ++kt) {
    const int cb = kt & 1;
    if (kt + 1 < nk) { asm volatile("s_waitcnt vmcnt(8)" ::: "memory"); }
    else             { asm volatile("s_waitcnt vmcnt(0)" ::: "memory"); }
    __builtin_amdgcn_s_barrier();       // tile kt resident for all waves

    short8 bf_[4][2];                   // ALL B n-frags: persist across phases
    short8 af_[4][2];                   // current A-half
    // ---- phase 0: B-all + A-half0 reads, then 32 MFMA ----
#pragma unroll
    for (int n_ = 0; n_ < 4; ++n_)
#pragma unroll
      for (int kk_ = 0; kk_ < 2; ++kk_) {
        int br_ = wc + n_ * 16 + fr;
        bf_[n_][kk_] = *(const short8*)&Bs[cb][br_][(kk_ * 32 + g * 8) ^ swa];
      }
#pragma unroll
    for (int i_ = 0; i_ < 4; ++i_)
#pragma unroll
      for (int kk_ = 0; kk_ < 2; ++kk_) {
        int ar_ = wr + i_ * 16 + fr;
        af_[i_][kk_] = *(const short8*)&As[cb][ar_][(kk_ * 32 + g * 8) ^ swa];
      }
    __builtin_amdgcn_s_barrier();
    __builtin_amdgcn_s_setprio(1);
#pragma unroll
    for (int i_ = 0; i_ < 4; ++i_)
#pragma unroll
      for (int n_ = 0; n_ < 4; ++n_)
#pragma unroll
        for (int kk_ = 0; kk_ < 2; ++kk_)
          acc[i_][n_] = __builtin_amdgcn_mfma_f32_16x16x32_bf16(
              af_[i_][kk_], bf_[n_][kk_], acc[i_][n_], 0, 0, 0);
    __builtin_amdgcn_s_setprio(0);
    __builtin_amdgcn_sched_barrier(0);
    // ---- phase 1: A-half1 reads (B cached), then 32 MFMA ----
#pragma unroll
    for (int i_ = 0; i_ < 4; ++i_)
#pragma unroll
      for (int kk_ = 0; kk_ < 2; ++kk_) {
        int ar_ = wr + 64 + i_ * 16 + fr;
        af_[i_][kk_] = *(const short8*)&As[cb][ar_][(kk_ * 32 + g * 8) ^ swa];
      }
    __builtin_amdgcn_s_barrier();
    __builtin_amdgcn_s_setprio(1);
#pragma unroll
    for (int i_ = 0; i_ < 4; ++i_)
#pragma unroll
      for (int n_ = 0; n_ < 4; ++n_)
#pragma unroll
        for (int kk_ = 0; kk_ < 2; ++kk_)
          acc[4 + i_][n_] = __builtin_amdgcn_mfma_f32_16x16x32_bf16(
              af_[i_][kk_], bf_[n_][kk_], acc[4 + i_][n_], 0, 0, 0);
    __builtin_amdgcn_s_setprio(0);
    __builtin_amdgcn_sched_barrier(0);

    __builtin_amdgcn_s_barrier();       // all waves done reading buf(kt&1)
    if (kt + 2 < nk) QSTAGE(cb, kt + 2);
  }
#undef QSTAGE

  // ---- epilogue: bias + RoPE scatter (q/k) or transposed V scatter ----
  if (bn < NQ + NKVD) {
    int ng0 = bn + wc;                  // one 64-col head per wave
    u16* hbase = (ng0 < NQ) ? qbuf + (long)(ng0 >> 6) * S_LEN * HD
                            : kbuf + (long)((ng0 - NQ) >> 6) * S_LEN * HD;
#pragma unroll
    for (int m = 0; m < 8; ++m)
#pragma unroll
      for (int rr = 0; rr < 4; ++rr) {
        int srow = bm + wr + m * 16 + fq + rr;
        const float* crow = cosb + (long)srow * HD;
        const float* srw  = sinb + (long)srow * HD;
#pragma unroll
        for (int j = 0; j < 2; ++j) {
          int dlo = j * 16 + fr;        // in [0,32)
          float c  = crow[dlo];
          float si = srw[dlo];
          float xl = acc[m][j][rr]     + bias[wc + j * 16 + fr];
          float xh = acc[m][j + 2][rr] + bias[wc + (j + 2) * 16 + fr];
          hbase[(long)srow * HD + dlo]      = f2bf(xl * c - xh * si);
          hbase[(long)srow * HD + dlo + 32] = f2bf(xh * c + xl * si);
        }
      }
  } else {
#pragma unroll
    for (int m = 0; m < 8; ++m)
#pragma unroll
      for (int n = 0; n < 4; ++n) {
        int ncol = wc + n * 16 + fr;
        int n3 = bn + ncol - NQ - NKVD;
        float bsv = bias[ncol];
#pragma unroll
        for (int rr = 0; rr < 4; ++rr) {
          int srow = bm + wr + m * 16 + fq + rr;
          vtbuf[(long)(n3 >> 6) * HD * S_LEN + (long)(n3 & 63) * S_LEN + srow] =
              f2bf(acc[m][n][rr] + bsv);
        }
      }
  }
}

// ---------------- 128x128 bf16 MFMA GEMM core (r7: ring-3 + counted vmcnt + swz) ----------------
__device__ __forceinline__ void gemm_tile(const u16* __restrict__ Abase, int lda,
                                          const u16* __restrict__ Bbase, int ldb,
                                          int kloop, floatx4 acc[4][4]) {
  __shared__ __align__(16) u16 As[3][128][32];
  __shared__ __align__(16) u16 Bs[3][128][32];
  const int t = threadIdx.x;
  const int w = t >> 6, l = t & 63;
  const int srow = w * 16 + (l >> 2);
  const int scol = (((l & 3) ^ ((l >> 3) & 3))) * 8;
  const int wr = (w >> 1) * 64, wc = (w & 1) * 64;
  const int fr = l & 15;
  const int fk8 = (((l >> 4) ^ ((l >> 1) & 3))) * 8;
  floatx4 zero = {0.f, 0.f, 0.f, 0.f};
#pragma unroll
  for (int i = 0; i < 4; ++i)
#pragma unroll
    for (int j = 0; j < 4; ++j) acc[i][j] = zero;

  const u16* Ar0 = Abase + (long)srow * lda + scol;
  const u16* Ar1 = Abase + (long)(64 + srow) * lda + scol;
  const u16* Br0 = Bbase + (long)srow * ldb + scol;
  const u16* Br1 = Bbase + (long)(64 + srow) * ldb + scol;

#define STAGE(buf, kt) do {                              \
    long ko_ = (long)(kt) * 32;                          \
    gl2lds16(Ar0 + ko_, &As[buf][w * 16][0]);            \
    gl2lds16(Ar1 + ko_, &As[buf][64 + w * 16][0]);       \
    gl2lds16(Br0 + ko_, &Bs[buf][w * 16][0]);            \
    gl2lds16(Br1 + ko_, &Bs[buf][64 + w * 16][0]);       \
  } while (0)

  const int nk = kloop >> 5;
  STAGE(0, 0);
  STAGE(1, 1);
  int cur = 0, nxt = 1, fut = 2;
  for (int kt = 0; kt < nk; ++kt) {
    if (kt + 1 < nk) { asm volatile("s_waitcnt vmcnt(4)" ::: "memory"); }
    else             { asm volatile("s_waitcnt vmcnt(0)" ::: "memory"); }
    asm volatile("s_barrier" ::: "memory");
    if (kt + 2 < nk) STAGE(fut, kt + 2);
    short8 af[4], bf8[4];
#pragma unroll
    for (int i = 0; i < 4; ++i) af[i] = *(const short8*)&As[cur][wr + i * 16 + fr][fk8];
#pragma unroll
    for (int j = 0; j < 4; ++j) bf8[j] = *(const short8*)&Bs[cur][wc + j * 16 + fr][fk8];
#pragma unroll
    for (int i = 0; i < 4; ++i)
#pragma unroll
      for (int j = 0; j < 4; ++j)
        acc[i][j] = __builtin_amdgcn_mfma_f32_16x16x32_bf16(af[i], bf8[j], acc[i][j], 0, 0, 0);
    int tmp = cur; cur = nxt; nxt = fut; fut = tmp;
  }
#undef STAGE
}

// ---------------- sliding-window GQA attention with sinks ----------------
__global__ __launch_bounds__(256) void k_attn(
    const u16* __restrict__ qb, const u16* __restrict__ kb, const u16* __restrict__ vtb,
    const float* __restrict__ sinks, u16* __restrict__ ao) {
  __shared__ __align__(16) u16 Kl[192][72];
  __shared__ __align__(16) u16 Vl[64][200];
  int t = threadIdx.x;
  int h = blockIdx.y, kvh = h >> 3;
  int qs = blockIdx.x * 64;
  int kstart = qs - 128;
  const u16* kbase = kb + (long)kvh * S_LEN * HD;
  const u16* vbase = vtb + (long)kvh * HD * S_LEN;
#pragma unroll
  for (int it = 0; it < 6; ++it) {
    int idx = t + it * 256;
    int c = idx >> 3, dc = (idx & 7) * 8;
    int j = kstart + c;
    short8 v = {0, 0, 0, 0, 0, 0, 0, 0};
    if (j >= 0) v = *(const short8*)(kbase + (long)j * HD + dc);
    *(short8*)&Kl[c][dc] = v;
  }
#pragma unroll
  for (int it = 0; it < 6; ++it) {
    int idx = t + it * 256;
    int d = idx / 24, c8 = idx % 24;
    int c = c8 * 8;
    int j = kstart + c;
    short8 v = {0, 0, 0, 0, 0, 0, 0, 0};
    if (j >= 0) v = *(const short8*)(vbase + (long)d * S_LEN + j);
    *(short8*)&Vl[d][c] = v;
  }
  __syncthreads();

  int w = t >> 6, l = t & 63;
  int fr = l & 15, fk8 = (l >> 4) * 8, fq = (l >> 4) * 4;
  const u16* qrow = qb + (long)h * S_LEN * HD + (long)(qs + w * 16 + fr) * HD;
  short8 a0 = *(const short8*)(qrow + fk8);
  short8 a1 = *(const short8*)(qrow + 32 + fk8);
  floatx4 sc[12];
#pragma unroll
  for (int ct = 0; ct < 12; ++ct) {
    floatx4 z = {0.f, 0.f, 0.f, 0.f};
    short8 b0 = *(const short8*)&Kl[ct * 16 + fr][fk8];
    short8 b1 = *(const short8*)&Kl[ct * 16 + fr][32 + fk8];
    z = __builtin_amdgcn_mfma_f32_16x16x32_bf16(a0, b0, z, 0, 0, 0);
    z = __builtin_amdgcn_mfma_f32_16x16x32_bf16(a1, b1, z, 0, 0, 0);
    sc[ct] = z;
  }
  __syncthreads();

  u16* Pw = &Kl[0][0] + w * 16 * 200;
  float snk = sinks[h];
#pragma unroll
  for (int r = 0; r < 4; ++r) {
    int rloc = w * 16 + fq + r;
    int cmin = rloc + 1;
    int jmin = 128 - qs;
    if (jmin > cmin) cmin = jmin;
    int cmax = rloc + 128;
    float vals[12];
    float mx = snk;
#pragma unroll
    for (int ct = 0; ct < 12; ++ct) {
      int c = ct * 16 + fr;
      float v = (c >= cmin && c <= cmax) ? sc[ct][r] * SCALE : -1e30f;
      vals[ct] = v;
      mx = fmaxf(mx, v);
    }
#pragma unroll
    for (int m = 1; m < 16; m <<= 1) mx = fmaxf(mx, __shfl_xor(mx, m));
    float e[12], sum = 0.f;
#pragma unroll
    for (int ct = 0; ct < 12; ++ct) { e[ct] = __expf(vals[ct] - mx); sum += e[ct]; }
#pragma unroll
    for (int m = 1; m < 16; m <<= 1) sum += __shfl_xor(sum, m);
    sum += __expf(snk - mx);
    float inv = 1.f / sum;
#pragma unroll
    for (int ct = 0; ct < 12; ++ct)
      Pw[(fq + r) * 200 + ct * 16 + fr] = f2bf(e[ct] * inv);
  }
  __syncthreads();

  floatx4 o[4];
  floatx4 zero = {0.f, 0.f, 0.f, 0.f};
#pragma unroll
  for (int cd = 0; cd < 4; ++cd) o[cd] = zero;
#pragma unroll
  for (int kk = 0; kk < 6; ++kk) {
    short8 pa = *(const short8*)(Pw + fr * 200 + kk * 32 + fk8);
#pragma unroll
    for (int cd = 0; cd < 4; ++cd) {
      short8 bv8 = *(const short8*)&Vl[cd * 16 + fr][kk * 32 + fk8];
      o[cd] = __builtin_amdgcn_mfma_f32_16x16x32_bf16(pa, bv8, o[cd], 0, 0, 0);
    }
  }
#pragma unroll
  for (int cd = 0; cd < 4; ++cd)
#pragma unroll
    for (int r = 0; r < 4; ++r) {
      int srow = qs + w * 16 + fq + r;
      ao[(long)srow * NQ + h * HD + cd * 16 + fr] = f2bf(o[cd][r]);
    }
}

// ---------------- output projection GEMM (r7 unchanged) ----------------
__global__ __launch_bounds__(256) void k_gemm_out(
    const u16* __restrict__ attn, const u16* __restrict__ wot,
    const float* __restrict__ bo, float* __restrict__ out) {
  int sw = xcd_swz(blockIdx.x, gridDim.x);
  int bm = (sw & 15) * 128, bn = (sw >> 4) * 128;
  floatx4 acc[4][4];
  gemm_tile(attn + (long)bm * NQ, NQ, wot + (long)bn * NQ, NQ, NQ, acc);
  int t = threadIdx.x, w = t >> 6, l = t & 63;
  int wr = (w >> 1) * 64, wc = (w & 1) * 64, fr = l & 15, fq = (l >> 4) * 4;
#pragma unroll
  for (int i = 0; i < 4; ++i)
#pragma unroll
    for (int j = 0; j < 4; ++j) {
      int ng = bn + wc + j * 16 + fr;
      if (ng >= HID) continue;
      float bsv = bo[ng];
#pragma unroll
      for (int r = 0; r < 4; ++r) {
        int srow = bm + wr + i * 16 + fq + r;
        out[(long)srow * HID + ng] = acc[i][j][r] + bsv;
      }
    }
}

extern "C" void kernel_launch(void* const* d_in, const int* in_sizes, int n_in,
                              void* d_out, int out_size, void* d_ws, size_t ws_size,
                              hipStream_t stream) {
  const float* hs    = (const float*)d_in[0];
  const float* cosb  = (const float*)d_in[1];
  const float* sinb  = (const float*)d_in[2];
  const float* wq    = (const float*)d_in[3];
  const float* bq    = (const float*)d_in[4];
  const float* wk    = (const float*)d_in[5];
  const float* bk    = (const float*)d_in[6];
  const float* wv    = (const float*)d_in[7];
  const float* bv    = (const float*)d_in[8];
  const float* wo    = (const float*)d_in[9];
  const float* bo    = (const float*)d_in[10];
  const float* sinks = (const float*)d_in[11];
  float* out = (float*)d_out;

  char* p = (char*)d_ws;
  u16* hsb   = (u16*)p; p += (size_t)S_LEN * HID * 2;
  u16* wqt   = (u16*)p; p += (size_t)NQ * HID * 2;
  u16* wkt   = (u16*)p; p += (size_t)NKVD * HID * 2;
  u16* wvt   = (u16*)p; p += (size_t)NKVD * HID * 2;
  u16* wot   = (u16*)p; p += (size_t)2944 * NQ * 2;
  u16* qbuf  = (u16*)p; p += (size_t)NH * S_LEN * HD * 2;
  u16* kbuf  = (u16*)p; p += (size_t)NKV * S_LEN * HD * 2;
  u16* vtbuf = (u16*)p; p += (size_t)NKV * HD * S_LEN * 2;
  u16* abuf  = (u16*)p; p += (size_t)S_LEN * NQ * 2;

  k_convert<<<(S_LEN * HID / 4 + 255) / 256, 256, 0, stream>>>(hs, hsb, S_LEN * HID / 4);
  k_transpose<<<dim3(NQ / 32, HID / 32), dim3(32, 8), 0, stream>>>(wq, wqt, HID, NQ);
  k_transpose<<<dim3(NKVD / 32, HID / 32), dim3(32, 8), 0, stream>>>(wk, wkt, HID, NKVD);
  k_transpose<<<dim3(NKVD / 32, HID / 32), dim3(32, 8), 0, stream>>>(wv, wvt, HID, NKVD);
  k_transpose<<<dim3(HID / 32, NQ / 32), dim3(32, 8), 0, stream>>>(wo, wot, NQ, HID);
  k_gemm_qkv256<<<8 * 20, 512, 0, stream>>>(
      hsb, wqt, wkt, wvt, bq, bk, bv, cosb, sinb, qbuf, kbuf, vtbuf);
  k_attn<<<dim3(S_LEN / 64, NH), 256, 0, stream>>>(qbuf, kbuf, vtbuf, sinks, abuf);
  k_gemm_out<<<23 * 16, 256, 0, stream>>>(abuf, wot, bo, out);
}